// Round 20
// baseline (126.303 us; speedup 1.0000x reference)
//
#include <hip/hip_runtime.h>
#include <math.h>

#define NV 4096      // variable nodes
#define MC 2048      // check nodes
#define DV 3
#define DC 6
#define NE (NV * DV) // 12288 edges
#define NB 2048      // batch
#define NITER 5
#define TPB 1024     // 16 waves/block; 2 blocks/CU -> 32 waves/CU (HW wave cap)

typedef float f32x2 __attribute__((ext_vector_type(2)));

// Build per-check-node edge lists (slot order arbitrary due to atomics).
__global__ __launch_bounds__(256) void build_cn(const int* __restrict__ cn_idx,
                                                int* __restrict__ cn_edges,
                                                int* __restrict__ cn_cnt) {
    int e = blockIdx.x * 256 + threadIdx.x;
    if (e < NE) {
        int m = cn_idx[e];
        int slot = atomicAdd(&cn_cnt[m], 1);
        cn_edges[m * DC + slot] = e;
    }
}

// Sort each CN's 6 edges ascending -> deterministic, matches ref edge order.
__global__ __launch_bounds__(256) void sort_cn(int* __restrict__ cn_edges) {
    int m = blockIdx.x * 256 + threadIdx.x;
    if (m < MC) {
        int v[DC];
        for (int j = 0; j < DC; ++j) v[j] = cn_edges[m * DC + j];
        for (int i = 1; i < DC; ++i) {
            int key = v[i]; int j = i - 1;
            while (j >= 0 && v[j] > key) { v[j + 1] = v[j]; --j; }
            v[j + 1] = key;
        }
        for (int j = 0; j < DC; ++j) cn_edges[m * DC + j] = v[j];
    }
}

// bare v_exp_f32 with -|x| folded as input modifier: u = 2^(-|x|)
static __device__ __forceinline__ float exp2_negabs(float x) {
    float r;
    asm volatile("v_exp_f32 %0, -abs(%1)" : "=v"(r) : "v"(x));
    return r;
}
// bare v_log_f32: log2(x)
static __device__ __forceinline__ float log2_raw(float x) {
    float r;
    asm volatile("v_log_f32 %0, %1" : "=v"(r) : "v"(x));
    return r;
}

// R18 structure (one sample/block, 48 KB edge-major LDS, two-phase barriers,
// (1024,8) -> 2 blocks/CU, vectorized VN phase) + MICRO-PACKED f32 CN chain:
// pair (a_j,b_j) and (P,M) as f32x2 so the product chain lowers to CDNA4
// VOP3P packed-f32 (v_pk_mul_f32: 2 FLOPs/slot). No packed ARRAYS beyond
// ab[6] (12 regs, replacing the scalar a[6]+bb[6]) -> no R11-style spill.
// Per-component arithmetic IEEE-identical to R18 [absmax 1.0 proven]:
//   u = 2^{-|mw2|}; ab = (1+u, max(1-u,1e-12)); PM = PROD ab
//   (Pb,Ma) = PM * swap(ab_j); num = Pb+Ma; den = max(Pb-Ma, 2^-23*Pb)
//   [den floor == ref clip at float32(1-1e-7) = 1-2^-23]
//   val2 = log2(num/den) >= 0; sign = bit parity (exact); out scaled by ln2.
__global__ __launch_bounds__(TPB, 8) void bp_iter(const float* __restrict__ noise_r,
                                                  const float* __restrict__ ew,
                                                  const int* __restrict__ cn_edges,
                                                  float* __restrict__ out) {
    __shared__ __align__(16) float msg[NE];
    const int b = blockIdx.x;
    const int t = threadIdx.x;

    const float NO    = (float)0.3981071705534972;         // 1/(R*2*10^(EbNo/10))
    const float NSTD  = sqrtf((float)(0.3981071705534972 * 0.5));
    const float LOG2E = 1.4426950408889634f;
    const float LN2   = 0.6931471805599453f;

    // Edge lists of this thread's 2 CNs (loop-invariant).
    int idx[MC / TPB][DC];
#pragma unroll
    for (int c = 0; c < MC / TPB; ++c)
#pragma unroll
        for (int j = 0; j < DC; ++j)
            idx[c][j] = cn_edges[(t + TPB * c) * DC + j];

    // Edge weights of this thread's 4 VNs (12 contiguous floats, hoisted).
    const float4 w0 = *(const float4*)&ew[12 * t + 0];
    const float4 w1 = *(const float4*)&ew[12 * t + 4];
    const float4 w2 = *(const float4*)&ew[12 * t + 8];

    // Channel LLRs (log2-scaled) for VNs 4t..4t+3.
    const float4 nz = *(const float4*)&noise_r[(size_t)b * NV + 4 * t];
    const float K = (4.0f / NO) * LOG2E;
    float l0 = K * (1.0f + NSTD * nz.x);
    float l1 = K * (1.0f + NSTD * nz.y);
    float l2 = K * (1.0f + NSTD * nz.z);
    float l3 = K * (1.0f + NSTD * nz.w);

    *(float4*)&msg[12 * t + 0] = make_float4(l0 * w0.x, l0 * w0.y, l0 * w0.z, l1 * w0.w);
    *(float4*)&msg[12 * t + 4] = make_float4(l1 * w1.x, l1 * w1.y, l2 * w1.z, l2 * w1.w);
    *(float4*)&msg[12 * t + 8] = make_float4(l2 * w2.x, l3 * w2.y, l3 * w2.z, l3 * w2.w);
    __syncthreads();

    for (int it = 0; it < NITER; ++it) {
        // ---- CN phase: each thread owns 2 check nodes ----
#pragma unroll
        for (int c = 0; c < MC / TPB; ++c) {
            f32x2 ab[DC];                       // (a_j, b_j)
            unsigned spack = 0u;
#pragma unroll
            for (int j = 0; j < DC; ++j) {
                float mw = msg[idx[c][j]];
                spack |= ((__float_as_uint(mw) >> 31) & 1u) << j;
                float u = exp2_negabs(mw);      // 2^{-|mw2|} = e^{-|mw|}
                ab[j].x = 1.0f + u;
                ab[j].y = fmaxf(1.0f - u, 1e-12f);
            }
            // exclusion-sign mask for all 6 edges at once (parity XOR, exact)
            const unsigned pmask = (__popc(spack) & 1u) ? (spack ^ 0x3Fu) : spack;

            f32x2 PM = {1.0f, 1.0f};            // (P, M)
#pragma unroll
            for (int j = 0; j < DC; ++j) PM *= ab[j];   // v_pk_mul_f32

#pragma unroll
            for (int j = 0; j < DC; ++j) {
                f32x2 sw = {ab[j].y, ab[j].x};          // swap -> op_sel
                f32x2 pb_ma = PM * sw;                  // (P*b_j, M*a_j) pk_mul
                float num = pb_ma.x + pb_ma.y;
                float den = fmaxf(pb_ma.x - pb_ma.y, 0x1.0p-23f * pb_ma.x);
                float val = log2_raw(__fdividef(num, den));   // >= 0, log2 dom
                msg[idx[c][j]] = __uint_as_float(__float_as_uint(val) |
                                                 (((pmask >> j) & 1u) << 31));
            }
        }
        __syncthreads();

        // ---- VN phase: 4 contiguous VNs -> 3x b128 read (+3x b128 write) ----
        float4 r0 = *(const float4*)&msg[12 * t + 0];
        float4 r1 = *(const float4*)&msg[12 * t + 4];
        float4 r2 = *(const float4*)&msg[12 * t + 8];
        float tot0 = l0 + ((r0.x + r0.y) + r0.z);
        float tot1 = l1 + ((r0.w + r1.x) + r1.y);
        float tot2 = l2 + ((r1.z + r1.w) + r2.x);
        float tot3 = l3 + ((r2.y + r2.z) + r2.w);

        if (it < NITER - 1) {
            *(float4*)&msg[12 * t + 0] = make_float4((tot0 - r0.x) * w0.x,
                                                     (tot0 - r0.y) * w0.y,
                                                     (tot0 - r0.z) * w0.z,
                                                     (tot1 - r0.w) * w0.w);
            *(float4*)&msg[12 * t + 4] = make_float4((tot1 - r1.x) * w1.x,
                                                     (tot1 - r1.y) * w1.y,
                                                     (tot2 - r1.z) * w1.z,
                                                     (tot2 - r1.w) * w1.w);
            *(float4*)&msg[12 * t + 8] = make_float4((tot2 - r2.x) * w2.x,
                                                     (tot3 - r2.y) * w2.y,
                                                     (tot3 - r2.z) * w2.z,
                                                     (tot3 - r2.w) * w2.w);
            __syncthreads();
        } else {
            *(float4*)&out[(size_t)b * NV + 4 * t] =
                make_float4(tot0 * LN2, tot1 * LN2, tot2 * LN2, tot3 * LN2);
        }
    }
}

extern "C" void kernel_launch(void* const* d_in, const int* in_sizes, int n_in,
                              void* d_out, int out_size, void* d_ws, size_t ws_size,
                              hipStream_t stream) {
    const float* noise_r = (const float*)d_in[0];
    // d_in[1] = noise_i (unused by reference)
    const float* ew      = (const float*)d_in[2];
    // d_in[3] = vn_idx: known structure e // 3 (edges contiguous per VN)
    const int*   cn_idx  = (const int*)d_in[4];
    float* out = (float*)d_out;

    int* cn_edges = (int*)d_ws;        // NE ints
    int* cn_cnt   = cn_edges + NE;     // MC ints

    hipMemsetAsync(cn_cnt, 0, MC * sizeof(int), stream);
    build_cn<<<(NE + 255) / 256, 256, 0, stream>>>(cn_idx, cn_edges, cn_cnt);
    sort_cn<<<(MC + 255) / 256, 256, 0, stream>>>(cn_edges);
    bp_iter<<<NB, TPB, 0, stream>>>(noise_r, ew, cn_edges, out);
}

// Round 21
// 118.720 us; speedup vs baseline: 1.0639x; 1.0639x over previous
//
#include <hip/hip_runtime.h>
#include <math.h>

#define NV 4096      // variable nodes
#define MC 2048      // check nodes
#define DV 3
#define DC 6
#define NE (NV * DV) // 12288 edges
#define NB 2048      // batch
#define NITER 5
#define TPB 1024     // 16 waves/block; 2 blocks/CU -> 32 waves/CU (HW wave cap)

// Build per-check-node edge lists (slot order arbitrary due to atomics).
__global__ __launch_bounds__(256) void build_cn(const int* __restrict__ cn_idx,
                                                int* __restrict__ cn_edges,
                                                int* __restrict__ cn_cnt) {
    int e = blockIdx.x * 256 + threadIdx.x;
    if (e < NE) {
        int m = cn_idx[e];
        int slot = atomicAdd(&cn_cnt[m], 1);
        cn_edges[m * DC + slot] = e;
    }
}

// Sort each CN's 6 edges ascending -> deterministic, matches ref edge order.
__global__ __launch_bounds__(256) void sort_cn(int* __restrict__ cn_edges) {
    int m = blockIdx.x * 256 + threadIdx.x;
    if (m < MC) {
        int v[DC];
        for (int j = 0; j < DC; ++j) v[j] = cn_edges[m * DC + j];
        for (int i = 1; i < DC; ++i) {
            int key = v[i]; int j = i - 1;
            while (j >= 0 && v[j] > key) { v[j + 1] = v[j]; --j; }
            v[j + 1] = key;
        }
        for (int j = 0; j < DC; ++j) cn_edges[m * DC + j] = v[j];
    }
}

// bare v_exp_f32 with -|x| folded as input modifier: u = 2^(-|x|)
static __device__ __forceinline__ float exp2_negabs(float x) {
    float r;
    asm volatile("v_exp_f32 %0, -abs(%1)" : "=v"(r) : "v"(x));
    return r;
}
// bare v_log_f32: log2(x)
static __device__ __forceinline__ float log2_raw(float x) {
    float r;
    asm volatile("v_log_f32 %0, %1" : "=v"(r) : "v"(x));
    return r;
}

// BEST configuration (R18, 119.5 us): one sample/block, 48 KB edge-major LDS,
// two-phase barriers, (1024,8) -> 2 blocks/CU = 32 waves (HW cap), scalar CN
// chain (packed-f32 attempts regressed: R11 fat-spill, R19 scalarized),
// vectorized VN phase (thread t owns VNs 4t..4t+3 -> 12 contiguous words ->
// 3x ds_read_b128 + 3x ds_write_b128; stride-12 b128 = 2-way bank alias =
// free). CN math in log2 domain [absmax 1.0 proven R13-R19]:
//   u = 2^{-|mw2|} (bare v_exp_f32, -|x| input modifier)
//   a = 1+u; b = max(1-u, 1e-12); P = PROD a; M = PROD b
//   val2_j = log2((P b_j + M a_j) / max(P b_j - M a_j, 2^-23 P b_j))
//            [den floor == ref clip at float32(1-1e-7) = 1-2^-23]
//   sign = bit parity XOR (exact == ref mod-2); final out scaled by ln2.
// Issue audit at 119.5 us: ~262K cy/CU modeled vs 287K wall (VALUBusy 90%)
// -> within ~9% of the VALU-issue roofline for this op count; trans count
// (3/edge) is the algebraic floor; occupancy at HW cap; conflicts intrinsic.
__global__ __launch_bounds__(TPB, 8) void bp_iter(const float* __restrict__ noise_r,
                                                  const float* __restrict__ ew,
                                                  const int* __restrict__ cn_edges,
                                                  float* __restrict__ out) {
    __shared__ __align__(16) float msg[NE];
    const int b = blockIdx.x;
    const int t = threadIdx.x;

    const float NO    = (float)0.3981071705534972;         // 1/(R*2*10^(EbNo/10))
    const float NSTD  = sqrtf((float)(0.3981071705534972 * 0.5));
    const float LOG2E = 1.4426950408889634f;
    const float LN2   = 0.6931471805599453f;

    // Edge lists of this thread's 2 CNs (loop-invariant).
    int idx[MC / TPB][DC];
#pragma unroll
    for (int c = 0; c < MC / TPB; ++c)
#pragma unroll
        for (int j = 0; j < DC; ++j)
            idx[c][j] = cn_edges[(t + TPB * c) * DC + j];

    // Edge weights of this thread's 4 VNs (12 contiguous floats, hoisted).
    const float4 w0 = *(const float4*)&ew[12 * t + 0];
    const float4 w1 = *(const float4*)&ew[12 * t + 4];
    const float4 w2 = *(const float4*)&ew[12 * t + 8];

    // Channel LLRs (log2-scaled) for VNs 4t..4t+3.
    const float4 nz = *(const float4*)&noise_r[(size_t)b * NV + 4 * t];
    const float K = (4.0f / NO) * LOG2E;
    float l0 = K * (1.0f + NSTD * nz.x);
    float l1 = K * (1.0f + NSTD * nz.y);
    float l2 = K * (1.0f + NSTD * nz.z);
    float l3 = K * (1.0f + NSTD * nz.w);

    *(float4*)&msg[12 * t + 0] = make_float4(l0 * w0.x, l0 * w0.y, l0 * w0.z, l1 * w0.w);
    *(float4*)&msg[12 * t + 4] = make_float4(l1 * w1.x, l1 * w1.y, l2 * w1.z, l2 * w1.w);
    *(float4*)&msg[12 * t + 8] = make_float4(l2 * w2.x, l3 * w2.y, l3 * w2.z, l3 * w2.w);
    __syncthreads();

    for (int it = 0; it < NITER; ++it) {
        // ---- CN phase: each thread owns 2 check nodes ----
#pragma unroll
        for (int c = 0; c < MC / TPB; ++c) {
            float a[DC], bb[DC];
            unsigned spack = 0u;
#pragma unroll
            for (int j = 0; j < DC; ++j) {
                float mw = msg[idx[c][j]];
                spack |= ((__float_as_uint(mw) >> 31) & 1u) << j;
                float u = exp2_negabs(mw);          // 2^{-|mw2|} = e^{-|mw|}
                a[j]  = 1.0f + u;
                bb[j] = fmaxf(1.0f - u, 1e-12f);
            }
            const unsigned par = __popc(spack) & 1u;

            float P = 1.0f, M = 1.0f;
#pragma unroll
            for (int j = 0; j < DC; ++j) {
                P *= a[j];
                M *= bb[j];
            }

#pragma unroll
            for (int j = 0; j < DC; ++j) {
                float Pb  = P * bb[j];
                float Ma  = M * a[j];
                float num = Pb + Ma;
                float den = fmaxf(Pb - Ma, 0x1.0p-23f * Pb);   // == ref clip 1-2^-23
                float val = log2_raw(__fdividef(num, den));    // >= 0, log2 domain
                msg[idx[c][j]] = __uint_as_float(__float_as_uint(val) |
                                                 (((par ^ (spack >> j)) & 1u) << 31));
            }
        }
        __syncthreads();

        // ---- VN phase: 4 contiguous VNs -> 3x b128 read (+3x b128 write) ----
        float4 r0 = *(const float4*)&msg[12 * t + 0];
        float4 r1 = *(const float4*)&msg[12 * t + 4];
        float4 r2 = *(const float4*)&msg[12 * t + 8];
        float tot0 = l0 + ((r0.x + r0.y) + r0.z);
        float tot1 = l1 + ((r0.w + r1.x) + r1.y);
        float tot2 = l2 + ((r1.z + r1.w) + r2.x);
        float tot3 = l3 + ((r2.y + r2.z) + r2.w);

        if (it < NITER - 1) {
            *(float4*)&msg[12 * t + 0] = make_float4((tot0 - r0.x) * w0.x,
                                                     (tot0 - r0.y) * w0.y,
                                                     (tot0 - r0.z) * w0.z,
                                                     (tot1 - r0.w) * w0.w);
            *(float4*)&msg[12 * t + 4] = make_float4((tot1 - r1.x) * w1.x,
                                                     (tot1 - r1.y) * w1.y,
                                                     (tot2 - r1.z) * w1.z,
                                                     (tot2 - r1.w) * w1.w);
            *(float4*)&msg[12 * t + 8] = make_float4((tot2 - r2.x) * w2.x,
                                                     (tot3 - r2.y) * w2.y,
                                                     (tot3 - r2.z) * w2.z,
                                                     (tot3 - r2.w) * w2.w);
            __syncthreads();
        } else {
            *(float4*)&out[(size_t)b * NV + 4 * t] =
                make_float4(tot0 * LN2, tot1 * LN2, tot2 * LN2, tot3 * LN2);
        }
    }
}

extern "C" void kernel_launch(void* const* d_in, const int* in_sizes, int n_in,
                              void* d_out, int out_size, void* d_ws, size_t ws_size,
                              hipStream_t stream) {
    const float* noise_r = (const float*)d_in[0];
    // d_in[1] = noise_i (unused by reference)
    const float* ew      = (const float*)d_in[2];
    // d_in[3] = vn_idx: known structure e // 3 (edges contiguous per VN)
    const int*   cn_idx  = (const int*)d_in[4];
    float* out = (float*)d_out;

    int* cn_edges = (int*)d_ws;        // NE ints
    int* cn_cnt   = cn_edges + NE;     // MC ints

    hipMemsetAsync(cn_cnt, 0, MC * sizeof(int), stream);
    build_cn<<<(NE + 255) / 256, 256, 0, stream>>>(cn_idx, cn_edges, cn_cnt);
    sort_cn<<<(MC + 255) / 256, 256, 0, stream>>>(cn_edges);
    bp_iter<<<NB, TPB, 0, stream>>>(noise_r, ew, cn_edges, out);
}